// Round 1
// baseline (631.285 us; speedup 1.0000x reference)
//
#include <hip/hip_runtime.h>
#include <stdint.h>

// ImportanceSparsification: per-batch top-k (k = 0.2*S*T) of 1/(cost+1e-8),
// mask=1 at selected, out = (source, target, cost*mask).
// Selection done as exact radix-select on f32 bit patterns of importance
// (positive floats: uint bit order == value order), with jax top_k tie-break
// (lowest flat index wins among equal values) handled exactly.

static constexpr int BINS0 = 2048;   // bits[31:21]
static constexpr int BINS1 = 2048;   // bits[20:10]
static constexpr int BINS2 = 1024;   // bits[9:0]
static constexpr int EQCAP = 16384;  // max gathered tie candidates per batch
static constexpr float EPSF = 1e-8f;

__device__ __forceinline__ uint32_t impBits(float c) {
    // IEEE-correct f32 divide (no fast-math) -> bit-exact vs numpy reference
    return __float_as_uint(1.0f / (c + EPSF));
}

// meta per batch: 16 u32
// [0]=prefix  [1]=krem  [2]=t  [3]=m  [4]=mult  [5]=idxthr  [6]=eqcnt  [7]=need

__global__ __launch_bounds__(256) void hist0_kernel(
    const float4* __restrict__ cost4, uint32_t* __restrict__ hist, int n4) {
    __shared__ uint32_t lh[BINS0];
    const int b = blockIdx.y;
    for (int i = threadIdx.x; i < BINS0; i += blockDim.x) lh[i] = 0;
    __syncthreads();
    const int idx = blockIdx.x * blockDim.x + threadIdx.x;
    float4 v = cost4[(size_t)b * n4 + idx];
    atomicAdd(&lh[impBits(v.x) >> 21], 1u);
    atomicAdd(&lh[impBits(v.y) >> 21], 1u);
    atomicAdd(&lh[impBits(v.z) >> 21], 1u);
    atomicAdd(&lh[impBits(v.w) >> 21], 1u);
    __syncthreads();
    uint32_t* gh = hist + (size_t)b * BINS0;
    for (int i = threadIdx.x; i < BINS0; i += blockDim.x)
        if (lh[i]) atomicAdd(&gh[i], lh[i]);
}

__global__ __launch_bounds__(256) void hist1_kernel(
    const float4* __restrict__ cost4, uint32_t* __restrict__ hist,
    const uint32_t* __restrict__ meta, int n4) {
    __shared__ uint32_t lh[BINS1];
    const int b = blockIdx.y;
    const uint32_t prefix = meta[b * 16 + 0];
    for (int i = threadIdx.x; i < BINS1; i += blockDim.x) lh[i] = 0;
    __syncthreads();
    const int idx = blockIdx.x * blockDim.x + threadIdx.x;
    float4 v = cost4[(size_t)b * n4 + idx];
    uint32_t bx;
    bx = impBits(v.x); if ((bx >> 21) == prefix) atomicAdd(&lh[(bx >> 10) & 0x7FF], 1u);
    bx = impBits(v.y); if ((bx >> 21) == prefix) atomicAdd(&lh[(bx >> 10) & 0x7FF], 1u);
    bx = impBits(v.z); if ((bx >> 21) == prefix) atomicAdd(&lh[(bx >> 10) & 0x7FF], 1u);
    bx = impBits(v.w); if ((bx >> 21) == prefix) atomicAdd(&lh[(bx >> 10) & 0x7FF], 1u);
    __syncthreads();
    uint32_t* gh = hist + (size_t)b * BINS1;
    for (int i = threadIdx.x; i < BINS1; i += blockDim.x)
        if (lh[i]) atomicAdd(&gh[i], lh[i]);
}

__global__ __launch_bounds__(256) void hist2_kernel(
    const float4* __restrict__ cost4, uint32_t* __restrict__ hist,
    const uint32_t* __restrict__ meta, int n4) {
    __shared__ uint32_t lh[BINS2];
    const int b = blockIdx.y;
    const uint32_t prefix = meta[b * 16 + 0];  // bits[31:10]
    for (int i = threadIdx.x; i < BINS2; i += blockDim.x) lh[i] = 0;
    __syncthreads();
    const int idx = blockIdx.x * blockDim.x + threadIdx.x;
    float4 v = cost4[(size_t)b * n4 + idx];
    uint32_t bx;
    bx = impBits(v.x); if ((bx >> 10) == prefix) atomicAdd(&lh[bx & 0x3FF], 1u);
    bx = impBits(v.y); if ((bx >> 10) == prefix) atomicAdd(&lh[bx & 0x3FF], 1u);
    bx = impBits(v.z); if ((bx >> 10) == prefix) atomicAdd(&lh[bx & 0x3FF], 1u);
    bx = impBits(v.w); if ((bx >> 10) == prefix) atomicAdd(&lh[bx & 0x3FF], 1u);
    __syncthreads();
    uint32_t* gh = hist + (size_t)b * BINS2;
    for (int i = threadIdx.x; i < BINS2; i += blockDim.x)
        if (lh[i]) atomicAdd(&gh[i], lh[i]);
}

__global__ void scan0_kernel(const uint32_t* __restrict__ hist,
                             uint32_t* __restrict__ meta, uint32_t K) {
    const int b = threadIdx.x;
    const uint32_t* h = hist + (size_t)b * BINS0;
    uint32_t krem = K;
    uint64_t cum = 0;
    uint32_t q = 0;
    for (int i = BINS0 - 1; i >= 0; --i) {
        uint32_t c = h[i];
        if (cum + c >= krem) { q = (uint32_t)i; krem -= (uint32_t)cum; break; }
        cum += c;
    }
    meta[b * 16 + 0] = q;
    meta[b * 16 + 1] = krem;
}

__global__ void scan1_kernel(const uint32_t* __restrict__ hist,
                             uint32_t* __restrict__ meta) {
    const int b = threadIdx.x;
    const uint32_t* h = hist + (size_t)b * BINS1;
    uint32_t krem = meta[b * 16 + 1];
    uint64_t cum = 0;
    uint32_t q = 0;
    for (int i = BINS1 - 1; i >= 0; --i) {
        uint32_t c = h[i];
        if (cum + c >= krem) { q = (uint32_t)i; krem -= (uint32_t)cum; break; }
        cum += c;
    }
    meta[b * 16 + 0] = (meta[b * 16 + 0] << 11) | q;
    meta[b * 16 + 1] = krem;
}

__global__ void scan2_kernel(const uint32_t* __restrict__ hist,
                             uint32_t* __restrict__ meta) {
    const int b = threadIdx.x;
    const uint32_t* h = hist + (size_t)b * BINS2;
    uint32_t krem = meta[b * 16 + 1];
    uint64_t cum = 0;
    uint32_t q = 0, mult = 0;
    for (int i = BINS2 - 1; i >= 0; --i) {
        uint32_t c = h[i];
        if (cum + c >= krem) { q = (uint32_t)i; krem -= (uint32_t)cum; mult = c; break; }
        cum += c;
    }
    const uint32_t t = (meta[b * 16 + 0] << 10) | q;
    const uint32_t need = (krem < mult) ? 1u : 0u;
    meta[b * 16 + 2] = t;
    meta[b * 16 + 3] = krem;   // m: number of threshold-equal elements to take
    meta[b * 16 + 4] = mult;
    meta[b * 16 + 5] = need ? 0u : 0xFFFFFFFFu;  // idxthr: all equals if no tie-break
    meta[b * 16 + 6] = 0;      // eqcnt
    meta[b * 16 + 7] = need;
}

__global__ __launch_bounds__(256) void gather_kernel(
    const float4* __restrict__ cost4, uint32_t* __restrict__ meta,
    uint32_t* __restrict__ eqbuf, int n4) {
    const int b = blockIdx.y;
    if (!meta[b * 16 + 7]) return;  // no tie-break needed
    const uint32_t t = meta[b * 16 + 2];
    const int idx = blockIdx.x * blockDim.x + threadIdx.x;
    float4 v = cost4[(size_t)b * n4 + idx];
    const uint32_t base = (uint32_t)idx * 4u;
    uint32_t* eb = eqbuf + (size_t)b * EQCAP;
    uint32_t bx;
    bx = impBits(v.x);
    if (bx == t) { uint32_t p = atomicAdd(&meta[b * 16 + 6], 1u); if (p < EQCAP) eb[p] = base + 0; }
    bx = impBits(v.y);
    if (bx == t) { uint32_t p = atomicAdd(&meta[b * 16 + 6], 1u); if (p < EQCAP) eb[p] = base + 1; }
    bx = impBits(v.z);
    if (bx == t) { uint32_t p = atomicAdd(&meta[b * 16 + 6], 1u); if (p < EQCAP) eb[p] = base + 2; }
    bx = impBits(v.w);
    if (bx == t) { uint32_t p = atomicAdd(&meta[b * 16 + 6], 1u); if (p < EQCAP) eb[p] = base + 3; }
}

// One block per batch: find m-th smallest flat index among gathered equals.
__global__ __launch_bounds__(256) void select_kernel(
    uint32_t* __restrict__ meta, const uint32_t* __restrict__ eqbuf, int N) {
    const int b = blockIdx.x;
    if (!meta[b * 16 + 7]) return;
    const uint32_t m = meta[b * 16 + 3];
    uint32_t mult = meta[b * 16 + 4];
    if (mult > (uint32_t)EQCAP) mult = EQCAP;
    const uint32_t* eb = eqbuf + (size_t)b * EQCAP;
    __shared__ uint32_t s[256];
    uint32_t lo = 0, hi = (uint32_t)N - 1;
    while (lo < hi) {
        const uint32_t mid = (lo + hi) >> 1;
        uint32_t c = 0;
        for (uint32_t j = threadIdx.x; j < mult; j += blockDim.x)
            c += (eb[j] <= mid) ? 1u : 0u;
        s[threadIdx.x] = c;
        __syncthreads();
        for (int st = 128; st > 0; st >>= 1) {
            if ((int)threadIdx.x < st) s[threadIdx.x] += s[threadIdx.x + st];
            __syncthreads();
        }
        const uint32_t tot = s[0];
        __syncthreads();
        if (tot >= m) hi = mid; else lo = mid + 1;
    }
    if (threadIdx.x == 0) meta[b * 16 + 5] = lo;
}

__global__ __launch_bounds__(256) void final_kernel(
    const float4* __restrict__ cost4, float4* __restrict__ out4,
    const uint32_t* __restrict__ meta, int n4) {
    const int b = blockIdx.y;
    const uint32_t t = meta[b * 16 + 2];
    const uint32_t idxthr = meta[b * 16 + 5];
    const int idx = blockIdx.x * blockDim.x + threadIdx.x;
    const size_t off = (size_t)b * n4 + idx;
    float4 v = cost4[off];
    const uint32_t base = (uint32_t)idx * 4u;
    float4 r;
    uint32_t bx;
    bx = impBits(v.x); r.x = (bx > t || (bx == t && base + 0 <= idxthr)) ? v.x : 0.0f;
    bx = impBits(v.y); r.y = (bx > t || (bx == t && base + 1 <= idxthr)) ? v.y : 0.0f;
    bx = impBits(v.z); r.z = (bx > t || (bx == t && base + 2 <= idxthr)) ? v.z : 0.0f;
    bx = impBits(v.w); r.w = (bx > t || (bx == t && base + 3 <= idxthr)) ? v.w : 0.0f;
    out4[off] = r;
}

extern "C" void kernel_launch(void* const* d_in, const int* in_sizes, int n_in,
                              void* d_out, int out_size, void* d_ws, size_t ws_size,
                              hipStream_t stream) {
    const float* src  = (const float*)d_in[0];
    const float* tgt  = (const float*)d_in[1];
    const float* cost = (const float*)d_in[2];
    const int srcN = in_sizes[0];
    const int tgtN = in_sizes[1];
    const int costN = in_sizes[2];
    const int S = 1024, T = 1024;
    const int N = S * T;
    const int B = costN / N;
    const uint32_t K = (uint32_t)(((uint64_t)N * 2ull) / 10ull);  // int(N*0.2) = 209715

    float* out = (float*)d_out;
    // outputs: [source | target | sparse_cost]
    hipMemcpyAsync(out, src, sizeof(float) * (size_t)srcN,
                   hipMemcpyDeviceToDevice, stream);
    hipMemcpyAsync(out + srcN, tgt, sizeof(float) * (size_t)tgtN,
                   hipMemcpyDeviceToDevice, stream);
    float* outCost = out + (size_t)srcN + tgtN;

    uint32_t* hist0 = (uint32_t*)d_ws;
    uint32_t* hist1 = hist0 + (size_t)B * BINS0;
    uint32_t* hist2 = hist1 + (size_t)B * BINS1;
    uint32_t* meta  = hist2 + (size_t)B * BINS2;
    uint32_t* eqbuf = meta + (size_t)B * 16;
    const size_t zeroBytes =
        sizeof(uint32_t) * ((size_t)B * (BINS0 + BINS1 + BINS2 + 16));
    hipMemsetAsync(d_ws, 0, zeroBytes, stream);

    const int n4 = N / 4;
    dim3 blk(256, 1, 1);
    dim3 grid(n4 / 256, B, 1);

    hist0_kernel<<<grid, blk, 0, stream>>>((const float4*)cost, hist0, n4);
    scan0_kernel<<<1, B, 0, stream>>>(hist0, meta, K);
    hist1_kernel<<<grid, blk, 0, stream>>>((const float4*)cost, hist1, meta, n4);
    scan1_kernel<<<1, B, 0, stream>>>(hist1, meta);
    hist2_kernel<<<grid, blk, 0, stream>>>((const float4*)cost, hist2, meta, n4);
    scan2_kernel<<<1, B, 0, stream>>>(hist2, meta);
    gather_kernel<<<grid, blk, 0, stream>>>((const float4*)cost, meta, eqbuf, n4);
    select_kernel<<<B, 256, 0, stream>>>(meta, eqbuf, N);
    final_kernel<<<grid, blk, 0, stream>>>((const float4*)cost, (float4*)outCost, meta, n4);
}

// Round 2
// 181.576 us; speedup vs baseline: 3.4767x; 3.4767x over previous
//
#include <hip/hip_runtime.h>
#include <stdint.h>

// ImportanceSparsification: per-batch top-k (k = 0.2*S*T) of 1/(cost+1e-8),
// mask=1 at selected, out = (source, target, cost*mask).
// Exact radix-select on f32 bit patterns of importance (positive floats:
// uint bit order == value order), jax top_k tie-break (lowest flat index
// first among equals) handled exactly.
//
// R1 -> R2: serial 16-thread scan kernels (3 x ~200us, dependent global
// loads) replaced by block-parallel suffix-scan (1 block/batch, 256 thr).

static constexpr int BINS0 = 2048;   // bits[31:21]
static constexpr int BINS1 = 2048;   // bits[20:10]
static constexpr int BINS2 = 1024;   // bits[9:0]
static constexpr int EQCAP = 16384;  // max gathered tie candidates per batch
static constexpr float EPSF = 1e-8f;

__device__ __forceinline__ uint32_t impBits(float c) {
    // IEEE-correct f32 divide (no fast-math) -> bit-exact vs numpy reference
    return __float_as_uint(1.0f / (c + EPSF));
}

// meta per batch: 16 u32
// [0]=prefix  [1]=krem  [2]=t  [3]=m  [4]=mult  [5]=idxthr  [6]=eqcnt  [7]=need

__global__ __launch_bounds__(256) void hist0_kernel(
    const float4* __restrict__ cost4, uint32_t* __restrict__ hist, int n4) {
    __shared__ uint32_t lh[BINS0];
    const int b = blockIdx.y;
    for (int i = threadIdx.x; i < BINS0; i += blockDim.x) lh[i] = 0;
    __syncthreads();
    const int idx = blockIdx.x * blockDim.x + threadIdx.x;
    float4 v = cost4[(size_t)b * n4 + idx];
    atomicAdd(&lh[impBits(v.x) >> 21], 1u);
    atomicAdd(&lh[impBits(v.y) >> 21], 1u);
    atomicAdd(&lh[impBits(v.z) >> 21], 1u);
    atomicAdd(&lh[impBits(v.w) >> 21], 1u);
    __syncthreads();
    uint32_t* gh = hist + (size_t)b * BINS0;
    for (int i = threadIdx.x; i < BINS0; i += blockDim.x)
        if (lh[i]) atomicAdd(&gh[i], lh[i]);
}

__global__ __launch_bounds__(256) void hist1_kernel(
    const float4* __restrict__ cost4, uint32_t* __restrict__ hist,
    const uint32_t* __restrict__ meta, int n4) {
    __shared__ uint32_t lh[BINS1];
    const int b = blockIdx.y;
    const uint32_t prefix = meta[b * 16 + 0];
    for (int i = threadIdx.x; i < BINS1; i += blockDim.x) lh[i] = 0;
    __syncthreads();
    const int idx = blockIdx.x * blockDim.x + threadIdx.x;
    float4 v = cost4[(size_t)b * n4 + idx];
    uint32_t bx;
    bx = impBits(v.x); if ((bx >> 21) == prefix) atomicAdd(&lh[(bx >> 10) & 0x7FF], 1u);
    bx = impBits(v.y); if ((bx >> 21) == prefix) atomicAdd(&lh[(bx >> 10) & 0x7FF], 1u);
    bx = impBits(v.z); if ((bx >> 21) == prefix) atomicAdd(&lh[(bx >> 10) & 0x7FF], 1u);
    bx = impBits(v.w); if ((bx >> 21) == prefix) atomicAdd(&lh[(bx >> 10) & 0x7FF], 1u);
    __syncthreads();
    uint32_t* gh = hist + (size_t)b * BINS1;
    for (int i = threadIdx.x; i < BINS1; i += blockDim.x)
        if (lh[i]) atomicAdd(&gh[i], lh[i]);
}

__global__ __launch_bounds__(256) void hist2_kernel(
    const float4* __restrict__ cost4, uint32_t* __restrict__ hist,
    const uint32_t* __restrict__ meta, int n4) {
    __shared__ uint32_t lh[BINS2];
    const int b = blockIdx.y;
    const uint32_t prefix = meta[b * 16 + 0];  // bits[31:10]
    for (int i = threadIdx.x; i < BINS2; i += blockDim.x) lh[i] = 0;
    __syncthreads();
    const int idx = blockIdx.x * blockDim.x + threadIdx.x;
    float4 v = cost4[(size_t)b * n4 + idx];
    uint32_t bx;
    bx = impBits(v.x); if ((bx >> 10) == prefix) atomicAdd(&lh[bx & 0x3FF], 1u);
    bx = impBits(v.y); if ((bx >> 10) == prefix) atomicAdd(&lh[bx & 0x3FF], 1u);
    bx = impBits(v.z); if ((bx >> 10) == prefix) atomicAdd(&lh[bx & 0x3FF], 1u);
    bx = impBits(v.w); if ((bx >> 10) == prefix) atomicAdd(&lh[bx & 0x3FF], 1u);
    __syncthreads();
    uint32_t* gh = hist + (size_t)b * BINS2;
    for (int i = threadIdx.x; i < BINS2; i += blockDim.x)
        if (lh[i]) atomicAdd(&gh[i], lh[i]);
}

// Block-parallel suffix-scan select: one block per batch.
// stage 0: bins=2048, krem=K        -> meta[0]=q,            meta[1]=krem'
// stage 1: bins=2048, krem=meta[1]  -> meta[0]=(meta0<<11)|q, meta[1]=krem'
// stage 2: bins=1024, krem=meta[1]  -> meta[2..7] finalized
__global__ __launch_bounds__(256) void scan_stage_kernel(
    const uint32_t* __restrict__ hist, uint32_t* __restrict__ meta,
    int bins, int stage, uint32_t K) {
    const int b = blockIdx.x;
    const uint32_t* h = hist + (size_t)b * bins;
    __shared__ uint32_t s[256];
    const int t = threadIdx.x;
    const int C = bins >> 8;  // 8 or 4 bins per thread
    const uint32_t krem = (stage == 0) ? K : meta[b * 16 + 1];

    uint32_t csum = 0;
    uint32_t hv[8];
    for (int i = 0; i < C; ++i) { hv[i] = h[t * C + i]; csum += hv[i]; }
    s[t] = csum;
    __syncthreads();
    // inclusive suffix scan (Hillis-Steele): s[t] = sum_{u>=t} csum_u
    for (int off = 1; off < 256; off <<= 1) {
        uint32_t add = (t + off < 256) ? s[t + off] : 0u;
        __syncthreads();
        s[t] += add;
        __syncthreads();
    }
    const uint32_t after = (t < 255) ? s[t + 1] : 0u;  // sum of chunks above mine
    // unique crossing thread: after < krem <= after + csum
    if (after < krem && after + csum >= krem) {
        uint32_t cum = after;
        for (int i = C - 1; i >= 0; --i) {
            const uint32_t c = hv[i];
            if (cum + c >= krem) {
                const uint32_t q = (uint32_t)(t * C + i);
                if (stage == 0) {
                    meta[b * 16 + 0] = q;
                    meta[b * 16 + 1] = krem - cum;
                } else if (stage == 1) {
                    meta[b * 16 + 0] = (meta[b * 16 + 0] << 11) | q;
                    meta[b * 16 + 1] = krem - cum;
                } else {
                    const uint32_t thr  = (meta[b * 16 + 0] << 10) | q;
                    const uint32_t m    = krem - cum;  // # of equals to take
                    const uint32_t mult = c;
                    const uint32_t need = (m < mult) ? 1u : 0u;
                    meta[b * 16 + 2] = thr;
                    meta[b * 16 + 3] = m;
                    meta[b * 16 + 4] = mult;
                    meta[b * 16 + 5] = need ? 0u : 0xFFFFFFFFu;
                    meta[b * 16 + 6] = 0u;
                    meta[b * 16 + 7] = need;
                }
                break;
            }
            cum += c;
        }
    }
}

__global__ __launch_bounds__(256) void gather_kernel(
    const float4* __restrict__ cost4, uint32_t* __restrict__ meta,
    uint32_t* __restrict__ eqbuf, int n4) {
    const int b = blockIdx.y;
    if (!meta[b * 16 + 7]) return;  // no tie-break needed
    const uint32_t t = meta[b * 16 + 2];
    const int idx = blockIdx.x * blockDim.x + threadIdx.x;
    float4 v = cost4[(size_t)b * n4 + idx];
    const uint32_t base = (uint32_t)idx * 4u;
    uint32_t* eb = eqbuf + (size_t)b * EQCAP;
    uint32_t bx;
    bx = impBits(v.x);
    if (bx == t) { uint32_t p = atomicAdd(&meta[b * 16 + 6], 1u); if (p < EQCAP) eb[p] = base + 0; }
    bx = impBits(v.y);
    if (bx == t) { uint32_t p = atomicAdd(&meta[b * 16 + 6], 1u); if (p < EQCAP) eb[p] = base + 1; }
    bx = impBits(v.z);
    if (bx == t) { uint32_t p = atomicAdd(&meta[b * 16 + 6], 1u); if (p < EQCAP) eb[p] = base + 2; }
    bx = impBits(v.w);
    if (bx == t) { uint32_t p = atomicAdd(&meta[b * 16 + 6], 1u); if (p < EQCAP) eb[p] = base + 3; }
}

// One block per batch: find m-th smallest flat index among gathered equals.
__global__ __launch_bounds__(256) void select_kernel(
    uint32_t* __restrict__ meta, const uint32_t* __restrict__ eqbuf, int N) {
    const int b = blockIdx.x;
    if (!meta[b * 16 + 7]) return;
    const uint32_t m = meta[b * 16 + 3];
    uint32_t mult = meta[b * 16 + 4];
    if (mult > (uint32_t)EQCAP) mult = EQCAP;
    const uint32_t* eb = eqbuf + (size_t)b * EQCAP;
    __shared__ uint32_t s[256];
    uint32_t lo = 0, hi = (uint32_t)N - 1;
    while (lo < hi) {
        const uint32_t mid = (lo + hi) >> 1;
        uint32_t c = 0;
        for (uint32_t j = threadIdx.x; j < mult; j += blockDim.x)
            c += (eb[j] <= mid) ? 1u : 0u;
        s[threadIdx.x] = c;
        __syncthreads();
        for (int st = 128; st > 0; st >>= 1) {
            if ((int)threadIdx.x < st) s[threadIdx.x] += s[threadIdx.x + st];
            __syncthreads();
        }
        const uint32_t tot = s[0];
        __syncthreads();
        if (tot >= m) hi = mid; else lo = mid + 1;
    }
    if (threadIdx.x == 0) meta[b * 16 + 5] = lo;
}

__global__ __launch_bounds__(256) void final_kernel(
    const float4* __restrict__ cost4, float4* __restrict__ out4,
    const uint32_t* __restrict__ meta, int n4) {
    const int b = blockIdx.y;
    const uint32_t t = meta[b * 16 + 2];
    const uint32_t idxthr = meta[b * 16 + 5];
    const int idx = blockIdx.x * blockDim.x + threadIdx.x;
    const size_t off = (size_t)b * n4 + idx;
    float4 v = cost4[off];
    const uint32_t base = (uint32_t)idx * 4u;
    float4 r;
    uint32_t bx;
    bx = impBits(v.x); r.x = (bx > t || (bx == t && base + 0 <= idxthr)) ? v.x : 0.0f;
    bx = impBits(v.y); r.y = (bx > t || (bx == t && base + 1 <= idxthr)) ? v.y : 0.0f;
    bx = impBits(v.z); r.z = (bx > t || (bx == t && base + 2 <= idxthr)) ? v.z : 0.0f;
    bx = impBits(v.w); r.w = (bx > t || (bx == t && base + 3 <= idxthr)) ? v.w : 0.0f;
    out4[off] = r;
}

extern "C" void kernel_launch(void* const* d_in, const int* in_sizes, int n_in,
                              void* d_out, int out_size, void* d_ws, size_t ws_size,
                              hipStream_t stream) {
    const float* src  = (const float*)d_in[0];
    const float* tgt  = (const float*)d_in[1];
    const float* cost = (const float*)d_in[2];
    const int srcN = in_sizes[0];
    const int tgtN = in_sizes[1];
    const int costN = in_sizes[2];
    const int S = 1024, T = 1024;
    const int N = S * T;
    const int B = costN / N;
    const uint32_t K = (uint32_t)(((uint64_t)N * 2ull) / 10ull);  // int(N*0.2) = 209715

    float* out = (float*)d_out;
    // outputs: [source | target | sparse_cost]
    hipMemcpyAsync(out, src, sizeof(float) * (size_t)srcN,
                   hipMemcpyDeviceToDevice, stream);
    hipMemcpyAsync(out + srcN, tgt, sizeof(float) * (size_t)tgtN,
                   hipMemcpyDeviceToDevice, stream);
    float* outCost = out + (size_t)srcN + tgtN;

    uint32_t* hist0 = (uint32_t*)d_ws;
    uint32_t* hist1 = hist0 + (size_t)B * BINS0;
    uint32_t* hist2 = hist1 + (size_t)B * BINS1;
    uint32_t* meta  = hist2 + (size_t)B * BINS2;
    uint32_t* eqbuf = meta + (size_t)B * 16;
    const size_t zeroBytes =
        sizeof(uint32_t) * ((size_t)B * (BINS0 + BINS1 + BINS2 + 16));
    hipMemsetAsync(d_ws, 0, zeroBytes, stream);

    const int n4 = N / 4;
    dim3 blk(256, 1, 1);
    dim3 grid(n4 / 256, B, 1);

    hist0_kernel<<<grid, blk, 0, stream>>>((const float4*)cost, hist0, n4);
    scan_stage_kernel<<<B, 256, 0, stream>>>(hist0, meta, BINS0, 0, K);
    hist1_kernel<<<grid, blk, 0, stream>>>((const float4*)cost, hist1, meta, n4);
    scan_stage_kernel<<<B, 256, 0, stream>>>(hist1, meta, BINS1, 1, K);
    hist2_kernel<<<grid, blk, 0, stream>>>((const float4*)cost, hist2, meta, n4);
    scan_stage_kernel<<<B, 256, 0, stream>>>(hist2, meta, BINS2, 2, K);
    gather_kernel<<<grid, blk, 0, stream>>>((const float4*)cost, meta, eqbuf, n4);
    select_kernel<<<B, 256, 0, stream>>>(meta, eqbuf, N);
    final_kernel<<<grid, blk, 0, stream>>>((const float4*)cost, (float4*)outCost, meta, n4);
}